// Round 9
// baseline (327.808 us; speedup 1.0000x reference)
//
#include <hip/hip_runtime.h>

// ---------------------------------------------------------------------------
// GAT (2-layer, dense mask) on gfx950 — R9 (= R8 with barrier alloc fix).
// R8 hung: barrier needs 4352 B (64+32*32 u32) but alloc/memset gave barC
// only 4 KB -> leaves 30/31 started 0xAA-poisoned -> gen never flipped ->
// deadlock. Now 8 KB per barrier, 16 KB memset. Everything else identical:
// 3 launches; kA = [packs+adj | gemm1], kB = R7 k_att1 (43.4 us, untouched),
// kC = [gemm2 | att2 | final]; two-level grid barrier (gen/root/leaf on
// separate lines, pollers spin on writer-free gen line with s_sleep).
// ---------------------------------------------------------------------------

typedef __attribute__((ext_vector_type(8))) short short8;   // 8 x bf16
typedef __attribute__((ext_vector_type(4))) float f32x4;
typedef unsigned long long u64;
typedef unsigned short u16;
typedef unsigned int u32;

__device__ __forceinline__ u16 f2bf_rne(float f){
  u32 u = __float_as_uint(f);
  return (u16)((u + 0x7fffu + ((u >> 16) & 1u)) >> 16);
}
__device__ __forceinline__ void async16(void* lds, const void* g){
  __builtin_amdgcn_global_load_lds((const __attribute__((address_space(1))) u32*)g,
                                   (__attribute__((address_space(3))) u32*)lds, 16, 0, 0);
}
__device__ __forceinline__ void async4(void* lds, const void* g){
  __builtin_amdgcn_global_load_lds((const __attribute__((address_space(1))) u32*)g,
                                   (__attribute__((address_space(3))) u32*)lds, 4, 0, 0);
}

// Two-level grid barrier for EXACTLY 1024 blocks (32 leaves x 32 blocks).
// bar[0]=gen (line 0), bar[32]=root (line 1), bar[64+l*32]=leaf l (own line).
// Needs 64+32*32 = 1088 u32 = 4352 B — callers allocate 8 KB, memset to 0.
__device__ __forceinline__ void grid_barrier(u32* bar){
  __syncthreads();
  if (threadIdx.x == 0){
    u32* gen  = bar;
    u32* root = bar + 32;
    u32* leaf = bar + 64 + (blockIdx.x & 31) * 32;
    u32 mygen = __hip_atomic_load(gen, __ATOMIC_RELAXED, __HIP_MEMORY_SCOPE_AGENT);
    __threadfence();                       // release my phase's writes
    u32 o = __hip_atomic_fetch_add(leaf, 1u, __ATOMIC_RELAXED, __HIP_MEMORY_SCOPE_AGENT);
    if (o == 31u){
      __hip_atomic_store(leaf, 0u, __ATOMIC_RELAXED, __HIP_MEMORY_SCOPE_AGENT);
      u32 r = __hip_atomic_fetch_add(root, 1u, __ATOMIC_RELAXED, __HIP_MEMORY_SCOPE_AGENT);
      if (r == 31u){
        __hip_atomic_store(root, 0u, __ATOMIC_RELAXED, __HIP_MEMORY_SCOPE_AGENT);
        __threadfence();
        __hip_atomic_fetch_add(gen, 1u, __ATOMIC_RELEASE, __HIP_MEMORY_SCOPE_AGENT);
      } else {
        while (__hip_atomic_load(gen, __ATOMIC_RELAXED, __HIP_MEMORY_SCOPE_AGENT) == mygen)
          __builtin_amdgcn_s_sleep(16);
      }
    } else {
      while (__hip_atomic_load(gen, __ATOMIC_RELAXED, __HIP_MEMORY_SCOPE_AGENT) == mygen)
        __builtin_amdgcn_s_sleep(16);
    }
    __threadfence();                       // acquire side
  }
  __syncthreads();
}

// ======================= kA: packs + adj | gemm1 ===========================
__global__ __launch_bounds__(256, 4) void k_gat_a(
    const float* __restrict__ x, const float* __restrict__ W,
    const int* __restrict__ adj, const float* __restrict__ av,
    u16* __restrict__ xA, u16* __restrict__ wB, u64* __restrict__ bits_t,
    u16* __restrict__ whB,
    float* __restrict__ e11, float* __restrict__ e102,
    float* __restrict__ e21, float* __restrict__ e202, u32* bar)
{
  __shared__ u16 tr[4096];
  const int tid = threadIdx.x, b = blockIdx.x;
  const int lane = tid & 63, wv = tid >> 6;
  const int row16 = lane & 15, grp = lane >> 4;

  // ---- P0a: x -> bf16 A-layout (all 1024 blocks) ----
  {
    int t = b * 256 + tid;                     // 262144
    int n = t & 4095, fg = t >> 12;
    const float* src = x + (size_t)n * 512 + fg * 8;
    float4 v0 = ((const float4*)src)[0];
    float4 v1 = ((const float4*)src)[1];
    u32 pk[4];
    pk[0] = f2bf_rne(v0.x) | ((u32)f2bf_rne(v0.y) << 16);
    pk[1] = f2bf_rne(v0.z) | ((u32)f2bf_rne(v0.w) << 16);
    pk[2] = f2bf_rne(v1.x) | ((u32)f2bf_rne(v1.y) << 16);
    pk[3] = f2bf_rne(v1.z) | ((u32)f2bf_rne(v1.w) << 16);
    *(uint4*)(xA + ((size_t)fg * 4096 + n) * 8) = *(uint4*)pk;
  }
  // ---- P0b: W -> bf16 B-layout (blocks 0..127) ----
  if (b < 128){
    int t = b * 256 + tid;                     // 32768
    int o = t & 63, fg = (t >> 6) & 63, h = t >> 12;
    const float* src = W + ((size_t)h * 512 + fg * 8) * 64 + o;
    u32 pk[4];
    #pragma unroll
    for (int p = 0; p < 4; ++p){
      u16 lo = f2bf_rne(src[(2 * p) * 64]);
      u16 hi = f2bf_rne(src[(2 * p + 1) * 64]);
      pk[p] = lo | ((u32)hi << 16);
    }
    *(uint4*)(wB + (size_t)h * 32768 + ((size_t)fg * 64 + o) * 8) = *(uint4*)pk;
  }
  // ---- P0c: adj -> transposed bitmask, contiguous-read order ----
  {
    int w = b * 4 + wv;                        // 0..4095
    #pragma unroll 4
    for (int k = 0; k < 64; ++k){
      int uid = w + k * 4096;                  // contiguous across waves
      int i = uid >> 6, jg = uid & 63;
      int v = adj[(size_t)i * 4096 + (jg << 6) + lane];
      u64 m = __ballot(v != 0);
      if (lane == 0) bits_t[(size_t)jg * 4096 + i] = m;
    }
  }
  grid_barrier(bar);

  // ---- P1: Wh = x @ W[h]; tables + whB pack (blocks 0..511) ----
  if (b < 512){
    int h = b >> 6, nblk = b & 63;
    int n0 = nblk * 64, n0w = n0 + wv * 16;
    const u16* wBh = wB + (size_t)h * 32768;
    f32x4 acc[4] = {};
    #pragma unroll 4
    for (int ks = 0; ks < 16; ++ks){
      int fgb = ks * 4 + grp;
      short8 af = *(const short8*)(xA + ((size_t)fgb * 4096 + n0w + row16) * 8);
      #pragma unroll
      for (int nt = 0; nt < 4; ++nt){
        short8 bf = *(const short8*)(wBh + ((size_t)fgb * 64 + nt * 16 + row16) * 8);
        acc[nt] = __builtin_amdgcn_mfma_f32_16x16x32_bf16(af, bf, acc[nt], 0, 0, 0);
      }
    }
    float a1v[4], a2v[4];
    #pragma unroll
    for (int nt = 0; nt < 4; ++nt){
      a1v[nt] = av[h * 128 + nt * 16 + row16];
      a2v[nt] = av[h * 128 + 64 + nt * 16 + row16];
    }
    #pragma unroll
    for (int r = 0; r < 4; ++r){
      float p1 = acc[0][r]*a1v[0] + acc[1][r]*a1v[1] + acc[2][r]*a1v[2] + acc[3][r]*a1v[3];
      float p2 = acc[0][r]*a2v[0] + acc[1][r]*a2v[1] + acc[2][r]*a2v[2] + acc[3][r]*a2v[3];
      #pragma unroll
      for (int d = 1; d < 16; d <<= 1){ p1 += __shfl_xor(p1, d, 64); p2 += __shfl_xor(p2, d, 64); }
      if (row16 == 0){
        int idx = h * 4096 + n0w + grp * 4 + r;
        e11[idx] = __expf(p1); e102[idx] = __expf(0.2f * p1);
        e21[idx] = __expf(p2); e202[idx] = __expf(0.2f * p2);
      }
    }
    #pragma unroll
    for (int nt = 0; nt < 4; ++nt)
      #pragma unroll
      for (int r = 0; r < 4; ++r){
        int jl = wv * 16 + grp * 4 + r;
        int o  = nt * 16 + row16;
        tr[((jl >> 3) * 64 + o) * 8 + (jl & 7)] = f2bf_rne(acc[nt][r]);
      }
    __syncthreads();
    u16* dst = whB + (size_t)h * 262144 + (size_t)n0 * 64;
    #pragma unroll
    for (int q = 0; q < 2; ++q)
      *(uint4*)(dst + (tid * 2 + q) * 8) = *(const uint4*)(tr + (tid * 2 + q) * 8);
  }
}

// ======================= kB: layer-1 attention (R7, unchanged) =============
__global__ __launch_bounds__(256) void k_att1(const u16* __restrict__ whB,
                                              const u64* __restrict__ bits_t,
                                              const float* __restrict__ e11, const float* __restrict__ e102,
                                              const float* __restrict__ e21, const float* __restrict__ e202,
                                              u16* __restrict__ pnum, float* __restrict__ pden){
  __shared__ u16  smB[2][4096];
  __shared__ float smT[2][2][64];
  __shared__ u32  smLut[4];
  int h     = blockIdx.y;
  int iblk  = blockIdx.x;
  int split = blockIdx.z;
  int lane = threadIdx.x & 63;
  int wv   = threadIdx.x >> 6;
  int row16 = lane & 15, grp = lane >> 4;
  if (threadIdx.x < 4)
    smLut[threadIdx.x] = ((threadIdx.x & 1) ? 0xFFFFu : 0u) | ((threadIdx.x & 2) ? 0xFFFF0000u : 0u);
  int i = iblk * 64 + wv * 16 + row16;
  int hoff = h * 4096;
  float f1  = e11[hoff + i];
  float f02 = e102[hoff + i];
  const u16* whBh = whB + (size_t)h * 262144;
  int jbeg = split * 1024;

  short8 bden;
  #pragma unroll
  for (int t = 0; t < 8; ++t) bden[t] = (row16 == 0) ? (short)0x3F80 : (short)0;

  auto stage = [&](int bb, int j0){
    const char* g = (const char*)whBh + (size_t)j0 * 128 + wv * 2048 + lane * 16;
    char* l = (char*)(&smB[bb][0]) + wv * 2048;
    async16(l, g);
    async16(l + 1024, g + 1024);
    if (wv == 0)      async4(&smT[bb][0][0], (const char*)(e21  + hoff + j0) + lane * 4);
    else if (wv == 1) async4(&smT[bb][1][0], (const char*)(e202 + hoff + j0) + lane * 4);
  };

  f32x4 acc[4] = {};
  f32x4 accden = {};
  stage(0, jbeg);
  for (int c = 0; c < 16; ++c){
    int bb = c & 1;
    u64 mrow = bits_t[(size_t)(split * 16 + c) * 4096 + i];
    __syncthreads();
    if (c < 15) stage(bb ^ 1, jbeg + (c + 1) * 64);
    #pragma unroll
    for (int ks = 0; ks < 2; ++ks){
      int kb = ks * 32 + grp * 8;
      float4 eA = *(const float4*)(&smT[bb][0][kb]);
      float4 eB = *(const float4*)(&smT[bb][0][kb + 4]);
      float4 gA = *(const float4*)(&smT[bb][1][kb]);
      float4 gB = *(const float4*)(&smT[bb][1][kb + 4]);
      float e1v[8] = {eA.x, eA.y, eA.z, eA.w, eB.x, eB.y, eB.z, eB.w};
      float e2v[8] = {gA.x, gA.y, gA.z, gA.w, gB.x, gB.y, gB.z, gB.w};
      const u16* bbase = &smB[bb][(ks * 4 + grp) * 512];
      short8 bf0 = *(const short8*)(bbase + (0 * 16 + row16) * 8);
      short8 bf1 = *(const short8*)(bbase + (1 * 16 + row16) * 8);
      short8 bf2 = *(const short8*)(bbase + (2 * 16 + row16) * 8);
      short8 bf3 = *(const short8*)(bbase + (3 * 16 + row16) * 8);
      u32 mb = ((u32)(mrow >> (ks * 32)) >> (grp * 8)) & 0xffu;
      u32 pk[4];
      #pragma unroll
      for (int t2i = 0; t2i < 4; ++t2i){
        float w0 = fmaxf(f1 * e1v[2 * t2i],     f02 * e2v[2 * t2i]);
        float w1 = fmaxf(f1 * e1v[2 * t2i + 1], f02 * e2v[2 * t2i + 1]);
        u32 p = __builtin_amdgcn_perm(__float_as_uint(w1), __float_as_uint(w0), 0x07060302u);
        pk[t2i] = p & smLut[(mb >> (2 * t2i)) & 3u];
      }
      short8 af = *(short8*)pk;
      acc[0] = __builtin_amdgcn_mfma_f32_16x16x32_bf16(af, bf0, acc[0], 0, 0, 0);
      acc[1] = __builtin_amdgcn_mfma_f32_16x16x32_bf16(af, bf1, acc[1], 0, 0, 0);
      acc[2] = __builtin_amdgcn_mfma_f32_16x16x32_bf16(af, bf2, acc[2], 0, 0, 0);
      acc[3] = __builtin_amdgcn_mfma_f32_16x16x32_bf16(af, bf3, acc[3], 0, 0, 0);
      accden = __builtin_amdgcn_mfma_f32_16x16x32_bf16(af, bden, accden, 0, 0, 0);
    }
  }

  #pragma unroll
  for (int r = 0; r < 4; ++r){
    int n = iblk * 64 + wv * 16 + grp * 4 + r;
    if (row16 == 0)
      pden[((size_t)split * 8 + h) * 4096 + n] = accden[r];
    u16* dst = pnum + ((size_t)split * 4096 + n) * 512 + h * 64 + row16;
    #pragma unroll
    for (int nt = 0; nt < 4; ++nt)
      dst[nt * 16] = f2bf_rne(acc[nt][r]);
  }
}

// ======================= kC: gemm2 | att2 | final ==========================
__global__ __launch_bounds__(256, 4) void k_gat_c(
    const u16* __restrict__ pnum1, const float* __restrict__ pden1,
    const float* __restrict__ Wout, const float* __restrict__ aout,
    const u64* __restrict__ bits_t,
    u16* __restrict__ whoB,
    float* __restrict__ e11o, float* __restrict__ e102o,
    float* __restrict__ e21o, float* __restrict__ e202o,
    float* __restrict__ pnum2, float* __restrict__ pden2,
    float* __restrict__ out, u32* bar)
{
  __shared__ __align__(16) char smem[10496];
  float* s_hrow = (float*)smem;               // 4 x 520 f32 = 8320 B
  float* s_red  = (float*)(smem + 8320);      // 256 f32 = 1024 B
  float* s_den  = (float*)(smem + 9344);      // 32 f32
  u32*   s_lut  = (u32*)(smem + 10240);       // 16 B
  const int tid = threadIdx.x, b = blockIdx.x;
  const int lane = tid & 63, wv = tid >> 6;
  const int row16 = lane & 15, grp = lane >> 4;

  if (tid < 4)
    s_lut[tid] = ((tid & 1) ? 0xFFFFu : 0u) | ((tid & 2) ? 0xFFFF0000u : 0u);

  // ---- P3: combine splits + elu + Who = h @ Wout + layer-2 tables ----
  {
    int n0 = b * 4;
    if (tid < 32){
      int hh = tid >> 2, nn = tid & 3;
      float d = 0.f;
      #pragma unroll
      for (int s = 0; s < 4; ++s) d += pden1[((size_t)s * 8 + hh) * 4096 + n0 + nn];
      s_den[tid] = d;
    }
    __syncthreads();
    {
      int nn = tid >> 6;                      // row 0..3
      int fo = (tid & 63) * 8;
      int hh = fo >> 6;
      float dinv = 1.f / s_den[hh * 4 + nn];
      float v[8] = {0.f,0.f,0.f,0.f,0.f,0.f,0.f,0.f};
      #pragma unroll
      for (int s = 0; s < 4; ++s){
        uint4 raw = *(const uint4*)(pnum1 + ((size_t)s * 4096 + n0 + nn) * 512 + fo);
        u32 rw[4] = {raw.x, raw.y, raw.z, raw.w};
        #pragma unroll
        for (int d2 = 0; d2 < 4; ++d2){
          v[d2 * 2]     += __uint_as_float(rw[d2] << 16);
          v[d2 * 2 + 1] += __uint_as_float(rw[d2] & 0xffff0000u);
        }
      }
      #pragma unroll
      for (int j = 0; j < 8; ++j){
        float val = v[j] * dinv;
        val = val > 0.f ? val : (__expf(val) - 1.f);
        s_hrow[nn * 520 + fo + j] = val;
      }
    }
    __syncthreads();
    {
      int c = tid & 15, rl = (tid >> 4) & 3, ks = tid >> 6;
      float acc = 0.f;
      #pragma unroll 8
      for (int f4 = 0; f4 < 32; ++f4){
        int f = ks * 128 + f4 * 4;
        float4 hv = *(const float4*)(s_hrow + rl * 520 + f);
        acc += hv.x * Wout[f * 16 + c] + hv.y * Wout[(f + 1) * 16 + c]
             + hv.z * Wout[(f + 2) * 16 + c] + hv.w * Wout[(f + 3) * 16 + c];
      }
      s_red[tid] = acc;
      __syncthreads();
      if (tid < 64){
        float total = acc + s_red[tid + 64] + s_red[tid + 128] + s_red[tid + 192];
        int n = n0 + rl;
        whoB[((size_t)(n >> 3) * 16 + c) * 8 + (n & 7)] = f2bf_rne(total);
        float p1 = total * aout[c], p2 = total * aout[16 + c];
        #pragma unroll
        for (int d = 1; d < 16; d <<= 1){ p1 += __shfl_xor(p1, d, 64); p2 += __shfl_xor(p2, d, 64); }
        if (c == 0){
          e11o[n] = __expf(p1); e102o[n] = __expf(0.2f * p1);
          e21o[n] = __expf(p2); e202o[n] = __expf(0.2f * p2);
        }
      }
    }
  }
  grid_barrier(bar);

  // ---- P4: layer-2 attention (global-direct, 16-way split) ----
  {
    int split = b >> 6, iblk = b & 63;
    int i = iblk * 64 + wv * 16 + row16;
    float f1  = e11o[i];
    float f02 = e102o[i];
    int jbeg = split * 256;
    short8 bden;
    #pragma unroll
    for (int t = 0; t < 8; ++t) bden[t] = (row16 == 0) ? (short)0x3F80 : (short)0;

    f32x4 acc = {};
    f32x4 accden = {};
    #pragma unroll
    for (int c = 0; c < 4; ++c){
      int j0 = jbeg + c * 64;
      u64 mrow = bits_t[(size_t)(split * 4 + c) * 4096 + i];
      #pragma unroll
      for (int ks = 0; ks < 2; ++ks){
        int sb = (j0 >> 3) + ks * 4 + grp;
        short8 bf = *(const short8*)(whoB + ((size_t)sb * 16 + row16) * 8);
        const float* t1 = e21o  + j0 + ks * 32 + grp * 8;
        const float* t2 = e202o + j0 + ks * 32 + grp * 8;
        float4 eA = *(const float4*)t1;
        float4 eB = *(const float4*)(t1 + 4);
        float4 gA = *(const float4*)t2;
        float4 gB = *(const float4*)(t2 + 4);
        float e1v[8] = {eA.x, eA.y, eA.z, eA.w, eB.x, eB.y, eB.z, eB.w};
        float e2v[8] = {gA.x, gA.y, gA.z, gA.w, gB.x, gB.y, gB.z, gB.w};
        u32 mb = ((u32)(mrow >> (ks * 32)) >> (grp * 8)) & 0xffu;
        u32 pk[4];
        #pragma unroll
        for (int t2i = 0; t2i < 4; ++t2i){
          float w0 = fmaxf(f1 * e1v[2 * t2i],     f02 * e2v[2 * t2i]);
          float w1 = fmaxf(f1 * e1v[2 * t2i + 1], f02 * e2v[2 * t2i + 1]);
          u32 p = __builtin_amdgcn_perm(__float_as_uint(w1), __float_as_uint(w0), 0x07060302u);
          pk[t2i] = p & s_lut[(mb >> (2 * t2i)) & 3u];
        }
        short8 af = *(short8*)pk;
        acc    = __builtin_amdgcn_mfma_f32_16x16x32_bf16(af, bf, acc, 0, 0, 0);
        accden = __builtin_amdgcn_mfma_f32_16x16x32_bf16(af, bden, accden, 0, 0, 0);
      }
    }
    #pragma unroll
    for (int r = 0; r < 4; ++r){
      int n = iblk * 64 + wv * 16 + grp * 4 + r;
      if (row16 == 0)
        pden2[(size_t)n * 16 + split] = accden[r];
      pnum2[((size_t)n * 16 + split) * 16 + row16] = acc[r];
    }
  }
  grid_barrier(bar);

  // ---- P5: combine + elu + log_softmax (blocks 0..255) ----
  if (b < 256){
    int t = b * 256 + tid;                    // 65536
    int c = t & 15;
    int n = t >> 4;
    float num = 0.f, den = 0.f;
    #pragma unroll
    for (int s = 0; s < 16; ++s){
      num += pnum2[((size_t)n * 16 + s) * 16 + c];
      den += pden2[(size_t)n * 16 + s];
    }
    float v = num / den;
    v = v > 0.f ? v : (__expf(v) - 1.f);
    float m = v;
    #pragma unroll
    for (int d = 1; d < 16; d <<= 1) m = fmaxf(m, __shfl_xor(m, d, 64));
    float es = __expf(v - m), ss = es;
    #pragma unroll
    for (int d = 1; d < 16; d <<= 1) ss += __shfl_xor(ss, d, 64);
    out[(size_t)n * 16 + c] = v - m - __logf(ss);
  }
}

// ---------------------------------------------------------------------------
extern "C" void kernel_launch(void* const* d_in, const int* in_sizes, int n_in,
                              void* d_out, int out_size, void* d_ws, size_t ws_size,
                              hipStream_t stream){
  (void)in_sizes; (void)n_in; (void)out_size; (void)ws_size;
  const float* x    = (const float*)d_in[0];
  const int*   adj  = (const int*)d_in[1];
  const float* W    = (const float*)d_in[2];
  const float* av   = (const float*)d_in[3];
  const float* Wout = (const float*)d_in[4];
  const float* aout = (const float*)d_in[5];
  float* out = (float*)d_out;
  char* ws = (char*)d_ws;

  u64*  bits_t  = (u64*)(ws + 0x0000000);        // 2 MB [64][4096]
  u16*  whB     = (u16*)(ws + 0x0200000);        // 4 MB
  float* e11    = (float*)(ws + 0x0600000);      // 4 x 128 KB exp tables
  float* e102   = (float*)(ws + 0x0620000);
  float* e21    = (float*)(ws + 0x0640000);
  float* e202   = (float*)(ws + 0x0660000);
  // overlap: xA/wB (kA only) alias pnum1 (written by kB)
  u16*  xA      = (u16*)(ws + 0x0680000);        // 4 MB
  u16*  wB      = (u16*)(ws + 0x0A80000);        // 512 KB
  u16*  pnum1   = (u16*)(ws + 0x0680000);        // 16 MB [4][4096][512] bf16
  float* pden1  = (float*)(ws + 0x1680000);      // 512 KB [4][8][4096]
  u16*  whoB    = (u16*)(ws + 0x1700000);        // 128 KB
  float* e11o   = (float*)(ws + 0x1720000);      // 4 x 16 KB
  float* e102o  = (float*)(ws + 0x1724000);
  float* e21o   = (float*)(ws + 0x1728000);
  float* e202o  = (float*)(ws + 0x172C000);
  float* pnum2  = (float*)(ws + 0x1730000);      // 4 MB [4096][16][16]
  float* pden2  = (float*)(ws + 0x1B30000);      // 256 KB
  u32*  barA    = (u32*)(ws + 0x1C00000);        // 8 KB (needs 4352 B)
  u32*  barC    = (u32*)(ws + 0x1C02000);        // 8 KB

  // barrier counters must start at 0 (ws is re-poisoned to 0xAA every call)
  hipMemsetAsync(ws + 0x1C00000, 0, 16384, stream);

  k_gat_a<<<dim3(1024), dim3(256), 0, stream>>>(x, W, adj, av, xA, wB, bits_t,
                                                whB, e11, e102, e21, e202, barA);
  k_att1<<<dim3(64, 8, 4), dim3(256), 0, stream>>>(whB, bits_t, e11, e102, e21, e202,
                                                   pnum1, pden1);
  k_gat_c<<<dim3(1024), dim3(256), 0, stream>>>(pnum1, pden1, Wout, aout, bits_t,
                                                whoB, e11o, e102o, e21o, e202o,
                                                pnum2, pden2, out, barC);
}

// Round 10
// 207.221 us; speedup vs baseline: 1.5819x; 1.5819x over previous
//
#include <hip/hip_runtime.h>

// ---------------------------------------------------------------------------
// GAT (2-layer, dense mask) on gfx950 — R10.
// vs R7 (192 us): k_att1 is LDS-BW-bound (16 b128 + 8 b32 per wave-chunk
// ~= measured 43 us) -> move e-tables from LDS to global (L1/L2 broadcast),
// halving hot LDS bytes. Scale-free weights w' = max(e^{s2}, e^{-0.8 s1}
// * e^{0.2 s2}) (row-scaling cancels in num/den) drop a table + a mul.
// adj-pack folded into k_gemm1 (overlaps MFMA); k_final folded into k_att2.
// 5 launches. Persistent-kernel grid barriers abandoned (R6/R9: 47-240 us
// per barrier from per-block device-scope fence L2 writeback/invalidate).
// ---------------------------------------------------------------------------

typedef __attribute__((ext_vector_type(8))) short short8;   // 8 x bf16
typedef __attribute__((ext_vector_type(4))) float f32x4;
typedef unsigned long long u64;
typedef unsigned short u16;
typedef unsigned int u32;

__device__ __forceinline__ u16 f2bf_rne(float f){
  u32 u = __float_as_uint(f);
  return (u16)((u + 0x7fffu + ((u >> 16) & 1u)) >> 16);
}
__device__ __forceinline__ void async16(void* lds, const void* g){
  __builtin_amdgcn_global_load_lds((const __attribute__((address_space(1))) u32*)g,
                                   (__attribute__((address_space(3))) u32*)lds, 16, 0, 0);
}

// ------------------------- K1: x-pack + W-pack -----------------------------
__global__ __launch_bounds__(256) void k_prep(const float* __restrict__ x,
                                              const float* __restrict__ W,
                                              u16* __restrict__ xA,
                                              u16* __restrict__ wB){
  if (blockIdx.x < 1024){
    int t = blockIdx.x * 256 + threadIdx.x;           // 262144
    int n = t & 4095, fg = t >> 12;
    const float* src = x + (size_t)n * 512 + fg * 8;
    float4 v0 = ((const float4*)src)[0];
    float4 v1 = ((const float4*)src)[1];
    u32 pk[4];
    pk[0] = f2bf_rne(v0.x) | ((u32)f2bf_rne(v0.y) << 16);
    pk[1] = f2bf_rne(v0.z) | ((u32)f2bf_rne(v0.w) << 16);
    pk[2] = f2bf_rne(v1.x) | ((u32)f2bf_rne(v1.y) << 16);
    pk[3] = f2bf_rne(v1.z) | ((u32)f2bf_rne(v1.w) << 16);
    *(uint4*)(xA + ((size_t)fg * 4096 + n) * 8) = *(uint4*)pk;
  } else {
    int t = (blockIdx.x - 1024) * 256 + threadIdx.x;  // 32768
    int o = t & 63, fg = (t >> 6) & 63, h = t >> 12;
    const float* src = W + ((size_t)h * 512 + fg * 8) * 64 + o;
    u32 pk[4];
    #pragma unroll
    for (int p = 0; p < 4; ++p){
      u16 lo = f2bf_rne(src[(2 * p) * 64]);
      u16 hi = f2bf_rne(src[(2 * p + 1) * 64]);
      pk[p] = lo | ((u32)hi << 16);
    }
    *(uint4*)(wB + (size_t)h * 32768 + ((size_t)fg * 64 + o) * 8) = *(uint4*)pk;
  }
}

// ------------- K2: Wh = x@W[h] + tables + whB pack + adj-pack slice --------
__global__ __launch_bounds__(256) void k_gemm1(const u16* __restrict__ xA,
                                               const u16* __restrict__ wB,
                                               const float* __restrict__ av,
                                               const int* __restrict__ adj,
                                               u16* __restrict__ whB,
                                               u64* __restrict__ bits_t,
                                               float* __restrict__ r1,
                                               float* __restrict__ e21, float* __restrict__ e202){
  __shared__ u16 tr[4096];                 // 64 x 64 bf16, whB sub-layout
  int h    = blockIdx.y;
  int nblk = blockIdx.x;
  int lane = threadIdx.x & 63;
  int wv   = threadIdx.x >> 6;
  int row16 = lane & 15, grp = lane >> 4;
  int n0 = nblk * 64;
  int n0w = n0 + wv * 16;
  const u16* wBh = wB + (size_t)h * 32768;
  f32x4 acc[4] = {};
  #pragma unroll 4
  for (int ks = 0; ks < 16; ++ks){
    int fgb = ks * 4 + grp;
    short8 af = *(const short8*)(xA + ((size_t)fgb * 4096 + n0w + row16) * 8);
    #pragma unroll
    for (int nt = 0; nt < 4; ++nt){
      short8 bf = *(const short8*)(wBh + ((size_t)fgb * 64 + nt * 16 + row16) * 8);
      acc[nt] = __builtin_amdgcn_mfma_f32_16x16x32_bf16(af, bf, acc[nt], 0, 0, 0);
    }
  }
  // ---- epilogue: scale-free score tables ----
  float a1v[4], a2v[4];
  #pragma unroll
  for (int nt = 0; nt < 4; ++nt){
    a1v[nt] = av[h * 128 + nt * 16 + row16];
    a2v[nt] = av[h * 128 + 64 + nt * 16 + row16];
  }
  #pragma unroll
  for (int r = 0; r < 4; ++r){
    float p1 = acc[0][r]*a1v[0] + acc[1][r]*a1v[1] + acc[2][r]*a1v[2] + acc[3][r]*a1v[3];
    float p2 = acc[0][r]*a2v[0] + acc[1][r]*a2v[1] + acc[2][r]*a2v[2] + acc[3][r]*a2v[3];
    #pragma unroll
    for (int d = 1; d < 16; d <<= 1){ p1 += __shfl_xor(p1, d, 64); p2 += __shfl_xor(p2, d, 64); }
    if (row16 == 0){
      int idx = h * 4096 + n0w + grp * 4 + r;
      r1[idx]   = __expf(-0.8f * p1);      // row scale e^{-0.8 s1}
      e21[idx]  = __expf(p2);
      e202[idx] = __expf(0.2f * p2);
    }
  }
  // ---- whB bf16 pack via LDS transpose ----
  #pragma unroll
  for (int nt = 0; nt < 4; ++nt)
    #pragma unroll
    for (int r = 0; r < 4; ++r){
      int jl = wv * 16 + grp * 4 + r;
      int o  = nt * 16 + row16;
      tr[((jl >> 3) * 64 + o) * 8 + (jl & 7)] = f2bf_rne(acc[nt][r]);
    }
  __syncthreads();
  u16* dst = whB + (size_t)h * 262144 + (size_t)n0 * 64;
  #pragma unroll
  for (int q = 0; q < 2; ++q)
    *(uint4*)(dst + (threadIdx.x * 2 + q) * 8) = *(const uint4*)(tr + (threadIdx.x * 2 + q) * 8);

  // ---- adj-pack slice: this block packs 8 adjacency rows (no data dep) ----
  {
    int B = blockIdx.y * 64 + blockIdx.x;   // 0..511
    int uid0 = B * 512 + wv * 128;
    for (int k = 0; k < 128; k += 8){
      int v[8];
      #pragma unroll
      for (int q = 0; q < 8; ++q){
        int uid = uid0 + k + q;
        v[q] = adj[(size_t)(uid >> 6) * 4096 + ((uid & 63) << 6) + lane];
      }
      u64 m[8];
      #pragma unroll
      for (int q = 0; q < 8; ++q) m[q] = __ballot(v[q] != 0);
      if (lane == 0){
        #pragma unroll
        for (int q = 0; q < 8; ++q){
          int uid = uid0 + k + q;
          bits_t[(size_t)(uid & 63) * 4096 + (uid >> 6)] = m[q];
        }
      }
    }
  }
}

// ------------------------- K3: layer-1 attention ---------------------------
// grid (64,8,4) = 2048 blocks; B-tile LDS dbuf; e-tables read from GLOBAL
// (grp-broadcast float4, L1/L2) to halve the LDS bottleneck.
__global__ __launch_bounds__(256) void k_att1(const u16* __restrict__ whB,
                                              const u64* __restrict__ bits_t,
                                              const float* __restrict__ r1,
                                              const float* __restrict__ e21, const float* __restrict__ e202,
                                              u16* __restrict__ pnum, float* __restrict__ pden){
  __shared__ u16  smB[2][4096];            // 64 j x 64 o, [j/8][o][j&7]
  __shared__ u32  smLut[4];
  int h     = blockIdx.y;
  int iblk  = blockIdx.x;
  int split = blockIdx.z;
  int lane = threadIdx.x & 63;
  int wv   = threadIdx.x >> 6;
  int row16 = lane & 15, grp = lane >> 4;
  if (threadIdx.x < 4)
    smLut[threadIdx.x] = ((threadIdx.x & 1) ? 0xFFFFu : 0u) | ((threadIdx.x & 2) ? 0xFFFF0000u : 0u);
  int i = iblk * 64 + wv * 16 + row16;
  int hoff = h * 4096;
  float r = r1[hoff + i];
  const u16* whBh = whB + (size_t)h * 262144;
  int jbeg = split * 1024;

  short8 bden;                             // ones-column B frag for den
  #pragma unroll
  for (int t = 0; t < 8; ++t) bden[t] = (row16 == 0) ? (short)0x3F80 : (short)0;

  auto stage = [&](int bb, int j0){
    const char* g = (const char*)whBh + (size_t)j0 * 128 + wv * 2048 + lane * 16;
    char* l = (char*)(&smB[bb][0]) + wv * 2048;
    async16(l, g);
    async16(l + 1024, g + 1024);
  };

  f32x4 acc[4] = {};
  f32x4 accden = {};
  stage(0, jbeg);
  for (int c = 0; c < 16; ++c){
    int bb = c & 1;
    int j0 = jbeg + c * 64;
    u64 mrow = bits_t[(size_t)(split * 16 + c) * 4096 + i];   // coalesced
    __syncthreads();                       // buf bb staged; buf bb^1 free
    if (c < 15) stage(bb ^ 1, j0 + 64);
    #pragma unroll
    for (int ks = 0; ks < 2; ++ks){
      const float* t1 = e21  + hoff + j0 + ks * 32 + grp * 8;   // global, grp-broadcast
      const float* t2 = e202 + hoff + j0 + ks * 32 + grp * 8;
      float4 eA = *(const float4*)t1;
      float4 eB = *(const float4*)(t1 + 4);
      float4 gA = *(const float4*)t2;
      float4 gB = *(const float4*)(t2 + 4);
      float e1v[8] = {eA.x, eA.y, eA.z, eA.w, eB.x, eB.y, eB.z, eB.w};
      float e2v[8] = {gA.x, gA.y, gA.z, gA.w, gB.x, gB.y, gB.z, gB.w};
      const u16* bbase = &smB[bb][(ks * 4 + grp) * 512];
      short8 bf0 = *(const short8*)(bbase + (0 * 16 + row16) * 8);
      short8 bf1 = *(const short8*)(bbase + (1 * 16 + row16) * 8);
      short8 bf2 = *(const short8*)(bbase + (2 * 16 + row16) * 8);
      short8 bf3 = *(const short8*)(bbase + (3 * 16 + row16) * 8);
      u32 mb = ((u32)(mrow >> (ks * 32)) >> (grp * 8)) & 0xffu;
      u32 pk[4];
      #pragma unroll
      for (int t2i = 0; t2i < 4; ++t2i){
        float w0 = fmaxf(e1v[2 * t2i],     r * e2v[2 * t2i]);
        float w1 = fmaxf(e1v[2 * t2i + 1], r * e2v[2 * t2i + 1]);
        u32 p = __builtin_amdgcn_perm(__float_as_uint(w1), __float_as_uint(w0), 0x07060302u);
        pk[t2i] = p & smLut[(mb >> (2 * t2i)) & 3u];
      }
      short8 af = *(short8*)pk;
      acc[0] = __builtin_amdgcn_mfma_f32_16x16x32_bf16(af, bf0, acc[0], 0, 0, 0);
      acc[1] = __builtin_amdgcn_mfma_f32_16x16x32_bf16(af, bf1, acc[1], 0, 0, 0);
      acc[2] = __builtin_amdgcn_mfma_f32_16x16x32_bf16(af, bf2, acc[2], 0, 0, 0);
      acc[3] = __builtin_amdgcn_mfma_f32_16x16x32_bf16(af, bf3, acc[3], 0, 0, 0);
      accden = __builtin_amdgcn_mfma_f32_16x16x32_bf16(af, bden, accden, 0, 0, 0);
    }
  }

  #pragma unroll
  for (int r4 = 0; r4 < 4; ++r4){
    int n = iblk * 64 + wv * 16 + grp * 4 + r4;
    if (row16 == 0)
      pden[((size_t)split * 8 + h) * 4096 + n] = accden[r4];
    u16* dst = pnum + ((size_t)split * 4096 + n) * 512 + h * 64 + row16;
    #pragma unroll
    for (int nt = 0; nt < 4; ++nt)
      dst[nt * 16] = f2bf_rne(acc[nt][r4]);
  }
}

// ------------------------- K4: combine + Who=h@Wout + layer-2 tables -------
__global__ __launch_bounds__(256) void k_gemm2(const u16* __restrict__ pnum,
                                               const float* __restrict__ pden,
                                               const float* __restrict__ Wout,
                                               const float* __restrict__ aout,
                                               u16* __restrict__ whoB,
                                               float* __restrict__ r1o,
                                               float* __restrict__ e21o, float* __restrict__ e202o){
  __shared__ float Wl[8192];                  // 512 x 16
  __shared__ float hrow[16 * 516];            // combined+elu rows, padded stride
  __shared__ float sden[128];                 // den[h][n]
  int n0 = blockIdx.x * 16;
  for (int t = threadIdx.x; t < 8192; t += 256) Wl[t] = Wout[t];
  if (threadIdx.x < 128){
    int hh = threadIdx.x >> 4, nn = threadIdx.x & 15;
    float d = 0.f;
    #pragma unroll
    for (int s = 0; s < 4; ++s) d += pden[((size_t)s * 8 + hh) * 4096 + n0 + nn];
    sden[threadIdx.x] = d;
  }
  __syncthreads();
  {
    int nn = threadIdx.x >> 4;
    int fc = threadIdx.x & 15;
    int f0 = fc * 32;
    int hh = fc >> 1;
    float dinv = 1.f / sden[hh * 16 + nn];
    float v[32];
    #pragma unroll
    for (int k = 0; k < 32; ++k) v[k] = 0.f;
    #pragma unroll
    for (int s = 0; s < 4; ++s){
      const u16* p = pnum + ((size_t)s * 4096 + n0 + nn) * 512 + f0;
      #pragma unroll
      for (int q = 0; q < 4; ++q){
        uint4 raw = *(const uint4*)(p + q * 8);
        u32 rw[4] = {raw.x, raw.y, raw.z, raw.w};
        #pragma unroll
        for (int d2 = 0; d2 < 4; ++d2){
          v[q * 8 + d2 * 2]     += __uint_as_float(rw[d2] << 16);
          v[q * 8 + d2 * 2 + 1] += __uint_as_float(rw[d2] & 0xffff0000u);
        }
      }
    }
    #pragma unroll
    for (int k = 0; k < 32; ++k){
      float val = v[k] * dinv;
      val = val > 0.f ? val : (__expf(val) - 1.f);
      hrow[nn * 516 + f0 + k] = val;
    }
  }
  __syncthreads();
  int c  = threadIdx.x & 15;
  int rl = threadIdx.x >> 4;
  int n = n0 + rl;
  const float4* hr = (const float4*)(hrow + rl * 516);
  float acc = 0.f;
  #pragma unroll 8
  for (int f4 = 0; f4 < 128; ++f4){
    float4 hv = hr[f4];
    int f = f4 * 4;
    acc += hv.x * Wl[f * 16 + c] + hv.y * Wl[(f + 1) * 16 + c]
         + hv.z * Wl[(f + 2) * 16 + c] + hv.w * Wl[(f + 3) * 16 + c];
  }
  whoB[((size_t)(n >> 3) * 16 + c) * 8 + (n & 7)] = f2bf_rne(acc);
  float p1 = acc * aout[c], p2 = acc * aout[16 + c];
  #pragma unroll
  for (int d = 1; d < 16; d <<= 1){ p1 += __shfl_xor(p1, d, 64); p2 += __shfl_xor(p2, d, 64); }
  if (c == 0){
    r1o[n]   = __expf(-0.8f * p1);
    e21o[n]  = __expf(p2);
    e202o[n] = __expf(0.2f * p2);
  }
}

// --------------- K5: layer-2 attention + elu + log_softmax (fused) ---------
// 256 blocks; block = 16 rows; 4 waves split j 4 x 1024; LDS combine.
__global__ __launch_bounds__(256) void k_att2f(const u16* __restrict__ whoB,
                                               const u64* __restrict__ bits_t,
                                               const float* __restrict__ r1o,
                                               const float* __restrict__ e21o, const float* __restrict__ e202o,
                                               float* __restrict__ out){
  __shared__ float s_acc[4][16][16];
  __shared__ float s_den[4][16];
  __shared__ u32 smLut[4];
  int n0 = blockIdx.x * 16;
  int tid = threadIdx.x;
  int lane = tid & 63, wv = tid >> 6;
  int row16 = lane & 15, grp = lane >> 4;
  if (tid < 4)
    smLut[tid] = ((tid & 1) ? 0xFFFFu : 0u) | ((tid & 2) ? 0xFFFF0000u : 0u);
  __syncthreads();
  int i = n0 + row16;
  float r = r1o[i];
  short8 bden;
  #pragma unroll
  for (int t = 0; t < 8; ++t) bden[t] = (row16 == 0) ? (short)0x3F80 : (short)0;

  f32x4 acc = {};
  f32x4 accden = {};
  int jbase = wv * 1024;
  for (int c = 0; c < 16; ++c){
    int j0 = jbase + c * 64;
    u64 mrow = bits_t[(size_t)(wv * 16 + c) * 4096 + i];
    #pragma unroll
    for (int ks = 0; ks < 2; ++ks){
      int sb = (j0 >> 3) + ks * 4 + grp;
      short8 bf = *(const short8*)(whoB + ((size_t)sb * 16 + row16) * 8);
      const float* t1 = e21o  + j0 + ks * 32 + grp * 8;
      const float* t2 = e202o + j0 + ks * 32 + grp * 8;
      float4 eA = *(const float4*)t1;
      float4 eB = *(const float4*)(t1 + 4);
      float4 gA = *(const float4*)t2;
      float4 gB = *(const float4*)(t2 + 4);
      float e1v[8] = {eA.x, eA.y, eA.z, eA.w, eB.x, eB.y, eB.z, eB.w};
      float e2v[8] = {gA.x, gA.y, gA.z, gA.w, gB.x, gB.y, gB.z, gB.w};
      u32 mb = ((u32)(mrow >> (ks * 32)) >> (grp * 8)) & 0xffu;
      u32 pk[4];
      #pragma unroll
      for (int t2i = 0; t2i < 4; ++t2i){
        float w0 = fmaxf(e1v[2 * t2i],     r * e2v[2 * t2i]);
        float w1 = fmaxf(e1v[2 * t2i + 1], r * e2v[2 * t2i + 1]);
        u32 p = __builtin_amdgcn_perm(__float_as_uint(w1), __float_as_uint(w0), 0x07060302u);
        pk[t2i] = p & smLut[(mb >> (2 * t2i)) & 3u];
      }
      short8 af = *(short8*)pk;
      acc    = __builtin_amdgcn_mfma_f32_16x16x32_bf16(af, bf, acc, 0, 0, 0);
      accden = __builtin_amdgcn_mfma_f32_16x16x32_bf16(af, bden, accden, 0, 0, 0);
    }
  }
  #pragma unroll
  for (int r4 = 0; r4 < 4; ++r4){
    s_acc[wv][grp * 4 + r4][row16] = acc[r4];
    if (row16 == 0) s_den[wv][grp * 4 + r4] = accden[r4];
  }
  __syncthreads();
  {
    int row = tid >> 4, c = tid & 15;
    float num = s_acc[0][row][c] + s_acc[1][row][c] + s_acc[2][row][c] + s_acc[3][row][c];
    float den = s_den[0][row] + s_den[1][row] + s_den[2][row] + s_den[3][row];
    float v = num / den;
    v = v > 0.f ? v : (__expf(v) - 1.f);
    float m = v;
    #pragma unroll
    for (int d = 1; d < 16; d <<= 1) m = fmaxf(m, __shfl_xor(m, d, 64));
    float es = __expf(v - m), ss = es;
    #pragma unroll
    for (int d = 1; d < 16; d <<= 1) ss += __shfl_xor(ss, d, 64);
    out[(size_t)(n0 + row) * 16 + c] = v - m - __logf(ss);
  }
}

// ---------------------------------------------------------------------------
extern "C" void kernel_launch(void* const* d_in, const int* in_sizes, int n_in,
                              void* d_out, int out_size, void* d_ws, size_t ws_size,
                              hipStream_t stream){
  (void)in_sizes; (void)n_in; (void)out_size; (void)ws_size;
  const float* x    = (const float*)d_in[0];
  const int*   adj  = (const int*)d_in[1];
  const float* W    = (const float*)d_in[2];
  const float* av   = (const float*)d_in[3];
  const float* Wout = (const float*)d_in[4];
  const float* aout = (const float*)d_in[5];
  float* out = (float*)d_out;
  char* ws = (char*)d_ws;

  u64*  bits_t  = (u64*)(ws + 0x0000000);        // 2 MB [64][4096]
  u16*  whB     = (u16*)(ws + 0x0200000);        // 4 MB
  float* r1     = (float*)(ws + 0x0600000);      // 128 KB
  float* e21    = (float*)(ws + 0x0620000);      // 128 KB
  float* e202   = (float*)(ws + 0x0640000);      // 128 KB
  // overlap: xA/wB (prep+gemm1 only) alias pnum1 (written by att1)
  u16*  xA      = (u16*)(ws + 0x0680000);        // 4 MB
  u16*  wB      = (u16*)(ws + 0x0A80000);        // 512 KB
  u16*  pnum1   = (u16*)(ws + 0x0680000);        // 16 MB [4][4096][512] bf16
  float* pden1  = (float*)(ws + 0x1680000);      // 512 KB [4][8][4096]
  u16*  whoB    = (u16*)(ws + 0x1700000);        // 128 KB
  float* r1o    = (float*)(ws + 0x1720000);      // 16 KB
  float* e21o   = (float*)(ws + 0x1724000);      // 16 KB
  float* e202o  = (float*)(ws + 0x1728000);      // 16 KB

  k_prep<<<dim3(1152), dim3(256), 0, stream>>>(x, W, xA, wB);
  k_gemm1<<<dim3(64, 8), dim3(256), 0, stream>>>(xA, wB, av, adj, whB, bits_t, r1, e21, e202);
  k_att1<<<dim3(64, 8, 4), dim3(256), 0, stream>>>(whB, bits_t, r1, e21, e202, pnum1, pden1);
  k_gemm2<<<dim3(256), dim3(256), 0, stream>>>(pnum1, pden1, Wout, aout, whoB, r1o, e21o, e202o);
  k_att2f<<<dim3(256), dim3(256), 0, stream>>>(whoB, bits_t, r1o, e21o, e202o, out);
}

// Round 11
// 175.404 us; speedup vs baseline: 1.8689x; 1.1814x over previous
//
#include <hip/hip_runtime.h>
#include <string.h>

// ---------------------------------------------------------------------------
// GAT (2-layer, dense mask) on gfx950 — R11.
// vs R7 (192 us, best): (1) all MFMA fragments switched bf16 -> f16 (same
// layout/bytes, better mantissa); (2) packed-f16 w-generation: tables stored
// f16 so one 16B read per octet and v_pk_mul/v_pk_max make 2 weights/inst;
// scale-free w' = max(e^{s2}, e^{-0.8 s1} e^{0.2 s2}) removes the perm
// repack entirely; (3) k_prep deleted — gemm1 self-stages W f32->f16 in LDS
// and loads x directly (2 float4 + cvt per A-frag); adj-pack stays in gemm1.
// 5 launches. R10's tables-in-global regressed (43->60) — tables back in LDS.
// ---------------------------------------------------------------------------

typedef _Float16 h2 __attribute__((ext_vector_type(2)));
typedef _Float16 half8 __attribute__((ext_vector_type(8)));
typedef __attribute__((ext_vector_type(4))) float f32x4;
typedef unsigned long long u64;
typedef unsigned short u16;
typedef unsigned int u32;

__device__ __forceinline__ u16 f2h(float f){
  union { _Float16 h; u16 u; } c; c.h = (_Float16)f; return c.u;
}
__device__ __forceinline__ h2 u2h2(u32 u){ union { u32 u; h2 h; } c; c.u = u; return c.h; }
__device__ __forceinline__ u32 h22u(h2 h){ union { u32 u; h2 h; } c; c.h = h; return c.u; }
__device__ __forceinline__ half8 pk2h8(uint4 v){ union { uint4 u; half8 h; } c; c.u = v; return c.h; }

__device__ __forceinline__ void async16(void* lds, const void* g){
  __builtin_amdgcn_global_load_lds((const __attribute__((address_space(1))) u32*)g,
                                   (__attribute__((address_space(3))) u32*)lds, 16, 0, 0);
}
__device__ __forceinline__ void async4(void* lds, const void* g){
  __builtin_amdgcn_global_load_lds((const __attribute__((address_space(1))) u32*)g,
                                   (__attribute__((address_space(3))) u32*)lds, 4, 0, 0);
}

// ===== K1: Wh = x @ W[h] (self-packing) + tables + whB + adj slice =========
// grid (64, 8); W[h] staged f32->f16 into LDS (64 KB, 2 blocks/CU);
// A-frags loaded straight from x (f32) and converted in-register.
__global__ __launch_bounds__(256) void k_gemm1(const float* __restrict__ x,
                                               const float* __restrict__ W,
                                               const float* __restrict__ av,
                                               const int* __restrict__ adj,
                                               u16* __restrict__ whB,
                                               u64* __restrict__ bits_t,
                                               float* __restrict__ r1,
                                               u16* __restrict__ e21h, u16* __restrict__ e202h){
  __shared__ u16 wLDS[32768];              // [fgb 0..63][o 0..63][q 0..7] f16, 64 KB
  __shared__ u16 tr[4096];                 // 8 KB transpose buffer
  int h    = blockIdx.y;
  int nblk = blockIdx.x;
  int tid  = threadIdx.x;
  int lane = tid & 63;
  int wv   = tid >> 6;
  int row16 = lane & 15, grp = lane >> 4;
  int n0 = nblk * 64;
  int n0w = n0 + wv * 16;

  // ---- stage W[h] f32 -> f16 B-layout in LDS ----
  {
    int o = tid & 63, fb0 = tid >> 6;      // 4 fgb per iteration
    for (int k = 0; k < 16; ++k){
      int fgb = fb0 + k * 4;
      const float* src = W + ((size_t)h * 512 + fgb * 8) * 64 + o;
      u32 pk[4];
      #pragma unroll
      for (int p = 0; p < 4; ++p)
        pk[p] = (u32)f2h(src[(2 * p) * 64]) | ((u32)f2h(src[(2 * p + 1) * 64]) << 16);
      *(uint4*)(wLDS + ((size_t)fgb * 64 + o) * 8) = *(uint4*)pk;
    }
  }
  __syncthreads();

  f32x4 acc[4] = {};
  #pragma unroll 4
  for (int ks = 0; ks < 16; ++ks){
    int fgb = ks * 4 + grp;
    const float* xs = x + (size_t)(n0w + row16) * 512 + fgb * 8;
    float4 xv0 = ((const float4*)xs)[0];
    float4 xv1 = ((const float4*)xs)[1];
    u32 ax[4];
    ax[0] = (u32)f2h(xv0.x) | ((u32)f2h(xv0.y) << 16);
    ax[1] = (u32)f2h(xv0.z) | ((u32)f2h(xv0.w) << 16);
    ax[2] = (u32)f2h(xv1.x) | ((u32)f2h(xv1.y) << 16);
    ax[3] = (u32)f2h(xv1.z) | ((u32)f2h(xv1.w) << 16);
    half8 af = pk2h8(*(uint4*)ax);
    #pragma unroll
    for (int nt = 0; nt < 4; ++nt){
      half8 bf = *(const half8*)(wLDS + ((size_t)fgb * 64 + nt * 16 + row16) * 8);
      acc[nt] = __builtin_amdgcn_mfma_f32_16x16x32_f16(af, bf, acc[nt], 0, 0, 0);
    }
  }
  // ---- scale-free score tables ----
  float a1v[4], a2v[4];
  #pragma unroll
  for (int nt = 0; nt < 4; ++nt){
    a1v[nt] = av[h * 128 + nt * 16 + row16];
    a2v[nt] = av[h * 128 + 64 + nt * 16 + row16];
  }
  #pragma unroll
  for (int r = 0; r < 4; ++r){
    float p1 = acc[0][r]*a1v[0] + acc[1][r]*a1v[1] + acc[2][r]*a1v[2] + acc[3][r]*a1v[3];
    float p2 = acc[0][r]*a2v[0] + acc[1][r]*a2v[1] + acc[2][r]*a2v[2] + acc[3][r]*a2v[3];
    #pragma unroll
    for (int d = 1; d < 16; d <<= 1){ p1 += __shfl_xor(p1, d, 64); p2 += __shfl_xor(p2, d, 64); }
    if (row16 == 0){
      int idx = h * 4096 + n0w + grp * 4 + r;
      r1[idx]    = __expf(-0.8f * p1);     // row scale e^{-0.8 s1}
      e21h[idx]  = f2h(__expf(p2));
      e202h[idx] = f2h(__expf(0.2f * p2));
    }
  }
  // ---- whB f16 pack via LDS transpose ----
  #pragma unroll
  for (int nt = 0; nt < 4; ++nt)
    #pragma unroll
    for (int r = 0; r < 4; ++r){
      int jl = wv * 16 + grp * 4 + r;
      int o  = nt * 16 + row16;
      tr[((jl >> 3) * 64 + o) * 8 + (jl & 7)] = f2h(acc[nt][r]);
    }
  __syncthreads();
  u16* dst = whB + (size_t)h * 262144 + (size_t)n0 * 64;
  #pragma unroll
  for (int q = 0; q < 2; ++q)
    *(uint4*)(dst + (tid * 2 + q) * 8) = *(const uint4*)(tr + (tid * 2 + q) * 8);

  // ---- adj-pack slice (transposed bitmask; no data dep on gemm) ----
  {
    int B = blockIdx.y * 64 + blockIdx.x;   // 0..511
    int uid0 = B * 512 + wv * 128;
    for (int k = 0; k < 128; k += 8){
      int v[8];
      #pragma unroll
      for (int q = 0; q < 8; ++q){
        int uid = uid0 + k + q;
        v[q] = adj[(size_t)(uid >> 6) * 4096 + ((uid & 63) << 6) + lane];
      }
      u64 m[8];
      #pragma unroll
      for (int q = 0; q < 8; ++q) m[q] = __ballot(v[q] != 0);
      if (lane == 0){
        #pragma unroll
        for (int q = 0; q < 8; ++q){
          int uid = uid0 + k + q;
          bits_t[(size_t)(uid & 63) * 4096 + (uid >> 6)] = m[q];
        }
      }
    }
  }
}

// ===== K2: layer-1 attention (R7 structure, f16 + packed w-gen) ============
// grid (64,8,4) = 2048 blocks, 8/CU; LDS dbuf B-tiles + f16 tables.
__global__ __launch_bounds__(256) void k_att1(const u16* __restrict__ whB,
                                              const u64* __restrict__ bits_t,
                                              const float* __restrict__ r1,
                                              const u16* __restrict__ e21h, const u16* __restrict__ e202h,
                                              u16* __restrict__ pnum, float* __restrict__ pden){
  __shared__ u16  smB[2][4096];            // 64 j x 64 o f16, [j/8][o][j&7]
  __shared__ u32  smT[2][2][64];           // staged f16 tables (256 B each)
  __shared__ u32  smLut[4];
  int h     = blockIdx.y;
  int iblk  = blockIdx.x;
  int split = blockIdx.z;
  int lane = threadIdx.x & 63;
  int wv   = threadIdx.x >> 6;
  int row16 = lane & 15, grp = lane >> 4;
  if (threadIdx.x < 4)
    smLut[threadIdx.x] = ((threadIdx.x & 1) ? 0xFFFFu : 0u) | ((threadIdx.x & 2) ? 0xFFFF0000u : 0u);
  int i = iblk * 64 + wv * 16 + row16;
  int hoff = h * 4096;
  u32 rb = (u32)f2h(r1[hoff + i]); rb |= rb << 16;
  h2 rr = u2h2(rb);
  const u16* whBh = whB + (size_t)h * 262144;
  int jbeg = split * 1024;

  half8 bden;                              // ones-column B frag for den
  {
    u32 z[4] = {0,0,0,0};
    if (row16 == 0){ z[0]=0x3C003C00u; z[1]=0x3C003C00u; z[2]=0x3C003C00u; z[3]=0x3C003C00u; }
    bden = pk2h8(*(uint4*)z);
  }

  auto stage = [&](int bb, int j0){
    const char* g = (const char*)whBh + (size_t)j0 * 128 + wv * 2048 + lane * 16;
    char* l = (char*)(&smB[bb][0]) + wv * 2048;
    async16(l, g);
    async16(l + 1024, g + 1024);
    // tables: one async4 covers 256 B (128 f16); we use the first 128 B (64 j)
    if (wv == 0)      async4(&smT[bb][0][0], (const char*)(e21h  + hoff + j0) + lane * 4);
    else if (wv == 1) async4(&smT[bb][1][0], (const char*)(e202h + hoff + j0) + lane * 4);
  };

  f32x4 acc[4] = {};
  f32x4 accden = {};
  stage(0, jbeg);
  for (int c = 0; c < 16; ++c){
    int bb = c & 1;
    u64 mrow = bits_t[(size_t)(split * 16 + c) * 4096 + i];   // coalesced
    __syncthreads();                       // buf bb staged; buf bb^1 free
    if (c < 15) stage(bb ^ 1, jbeg + (c + 1) * 64);
    #pragma unroll
    for (int ks = 0; ks < 2; ++ks){
      uint4 e1q = *(const uint4*)((const char*)&smT[bb][0][0] + ks * 64 + grp * 16);
      uint4 e2q = *(const uint4*)((const char*)&smT[bb][1][0] + ks * 64 + grp * 16);
      u32 es[4] = {e1q.x, e1q.y, e1q.z, e1q.w};
      u32 gs[4] = {e2q.x, e2q.y, e2q.z, e2q.w};
      const u16* bbase = &smB[bb][(ks * 4 + grp) * 512];
      half8 bf0 = *(const half8*)(bbase + (0 * 16 + row16) * 8);
      half8 bf1 = *(const half8*)(bbase + (1 * 16 + row16) * 8);
      half8 bf2 = *(const half8*)(bbase + (2 * 16 + row16) * 8);
      half8 bf3 = *(const half8*)(bbase + (3 * 16 + row16) * 8);
      u32 mb = ((u32)(mrow >> (ks * 32)) >> (grp * 8)) & 0xffu;
      u32 pk[4];
      #pragma unroll
      for (int t2i = 0; t2i < 4; ++t2i){
        h2 w = __builtin_elementwise_max(u2h2(es[t2i]), rr * u2h2(gs[t2i]));
        pk[t2i] = h22u(w) & smLut[(mb >> (2 * t2i)) & 3u];
      }
      half8 af = pk2h8(*(uint4*)pk);
      acc[0] = __builtin_amdgcn_mfma_f32_16x16x32_f16(af, bf0, acc[0], 0, 0, 0);
      acc[1] = __builtin_amdgcn_mfma_f32_16x16x32_f16(af, bf1, acc[1], 0, 0, 0);
      acc[2] = __builtin_amdgcn_mfma_f32_16x16x32_f16(af, bf2, acc[2], 0, 0, 0);
      acc[3] = __builtin_amdgcn_mfma_f32_16x16x32_f16(af, bf3, acc[3], 0, 0, 0);
      accden = __builtin_amdgcn_mfma_f32_16x16x32_f16(af, bden, accden, 0, 0, 0);
    }
  }

  #pragma unroll
  for (int r4 = 0; r4 < 4; ++r4){
    int n = iblk * 64 + wv * 16 + grp * 4 + r4;
    if (row16 == 0)
      pden[((size_t)split * 8 + h) * 4096 + n] = accden[r4];
    u16* dst = pnum + ((size_t)split * 4096 + n) * 512 + h * 64 + row16;
    #pragma unroll
    for (int nt = 0; nt < 4; ++nt)
      dst[nt * 16] = f2h(acc[nt][r4]);
  }
}

// ===== K3: combine + Who = h @ Wout + layer-2 tables =======================
__global__ __launch_bounds__(256) void k_gemm2(const u16* __restrict__ pnum,
                                               const float* __restrict__ pden,
                                               const float* __restrict__ Wout,
                                               const float* __restrict__ aout,
                                               u16* __restrict__ whoB,
                                               float* __restrict__ r1o,
                                               u16* __restrict__ e21oh, u16* __restrict__ e202oh){
  __shared__ float Wl[8192];                  // 512 x 16
  __shared__ float hrow[16 * 516];            // combined+elu rows, padded stride
  __shared__ float sden[128];                 // den[h][n]
  int n0 = blockIdx.x * 16;
  for (int t = threadIdx.x; t < 8192; t += 256) Wl[t] = Wout[t];
  if (threadIdx.x < 128){
    int hh = threadIdx.x >> 4, nn = threadIdx.x & 15;
    float d = 0.f;
    #pragma unroll
    for (int s = 0; s < 4; ++s) d += pden[((size_t)s * 8 + hh) * 4096 + n0 + nn];
    sden[threadIdx.x] = d;
  }
  __syncthreads();
  {
    int nn = threadIdx.x >> 4;
    int fc = threadIdx.x & 15;
    int f0 = fc * 32;
    int hh = fc >> 1;
    float dinv = 1.f / sden[hh * 16 + nn];
    float v[32];
    #pragma unroll
    for (int k = 0; k < 32; ++k) v[k] = 0.f;
    #pragma unroll
    for (int s = 0; s < 4; ++s){
      const u16* p = pnum + ((size_t)s * 4096 + n0 + nn) * 512 + f0;
      #pragma unroll
      for (int q = 0; q < 4; ++q){
        uint4 raw = *(const uint4*)(p + q * 8);
        u32 rw[4] = {raw.x, raw.y, raw.z, raw.w};
        #pragma unroll
        for (int d2 = 0; d2 < 4; ++d2){
          h2 dh = u2h2(rw[d2]);
          v[q * 8 + d2 * 2]     += (float)dh.x;
          v[q * 8 + d2 * 2 + 1] += (float)dh.y;
        }
      }
    }
    #pragma unroll
    for (int k = 0; k < 32; ++k){
      float val = v[k] * dinv;
      val = val > 0.f ? val : (__expf(val) - 1.f);
      hrow[nn * 516 + f0 + k] = val;
    }
  }
  __syncthreads();
  int c  = threadIdx.x & 15;
  int rl = threadIdx.x >> 4;
  int n = n0 + rl;
  const float4* hr = (const float4*)(hrow + rl * 516);
  float acc = 0.f;
  #pragma unroll 8
  for (int f4 = 0; f4 < 128; ++f4){
    float4 hv = hr[f4];
    int f = f4 * 4;
    acc += hv.x * Wl[f * 16 + c] + hv.y * Wl[(f + 1) * 16 + c]
         + hv.z * Wl[(f + 2) * 16 + c] + hv.w * Wl[(f + 3) * 16 + c];
  }
  whoB[((size_t)(n >> 3) * 16 + c) * 8 + (n & 7)] = f2h(acc);
  float p1 = acc * aout[c], p2 = acc * aout[16 + c];
  #pragma unroll
  for (int d = 1; d < 16; d <<= 1){ p1 += __shfl_xor(p1, d, 64); p2 += __shfl_xor(p2, d, 64); }
  if (c == 0){
    r1o[n]    = __expf(-0.8f * p1);
    e21oh[n]  = f2h(__expf(p2));
    e202oh[n] = f2h(__expf(0.2f * p2));
  }
}

// ===== K4: layer-2 attention (16-way split, f16, global-direct) ============
__global__ __launch_bounds__(256) void k_att2(const u16* __restrict__ whoB,
                                              const u64* __restrict__ bits_t,
                                              const float* __restrict__ r1o,
                                              const u16* __restrict__ e21oh, const u16* __restrict__ e202oh,
                                              float* __restrict__ pnum, float* __restrict__ pden){
  __shared__ u32 smLut[4];
  int iblk  = blockIdx.x;
  int split = blockIdx.y;                     // 0..15
  int lane = threadIdx.x & 63;
  int wv   = threadIdx.x >> 6;
  int row16 = lane & 15, grp = lane >> 4;
  if (threadIdx.x < 4)
    smLut[threadIdx.x] = ((threadIdx.x & 1) ? 0xFFFFu : 0u) | ((threadIdx.x & 2) ? 0xFFFF0000u : 0u);
  __syncthreads();
  int i = iblk * 64 + wv * 16 + row16;
  u32 rb = (u32)f2h(r1o[i]); rb |= rb << 16;
  h2 rr = u2h2(rb);
  int jbeg = split * 256;
  half8 bden;
  {
    u32 z[4] = {0,0,0,0};
    if (row16 == 0){ z[0]=0x3C003C00u; z[1]=0x3C003C00u; z[2]=0x3C003C00u; z[3]=0x3C003C00u; }
    bden = pk2h8(*(uint4*)z);
  }

  f32x4 acc = {};
  f32x4 accden = {};
  #pragma unroll
  for (int c = 0; c < 4; ++c){
    int j0 = jbeg + c * 64;
    u64 mrow = bits_t[(size_t)(split * 4 + c) * 4096 + i];   // coalesced
    #pragma unroll
    for (int ks = 0; ks < 2; ++ks){
      int sb = (j0 >> 3) + ks * 4 + grp;
      half8 bf = *(const half8*)(whoB + ((size_t)sb * 16 + row16) * 8);
      uint4 e1q = *(const uint4*)(e21oh  + j0 + ks * 32 + grp * 8);
      uint4 e2q = *(const uint4*)(e202oh + j0 + ks * 32 + grp * 8);
      u32 es[4] = {e1q.x, e1q.y, e1q.z, e1q.w};
      u32 gs[4] = {e2q.x, e2q.y, e2q.z, e2q.w};
      u32 mb = ((u32)(mrow >> (ks * 32)) >> (grp * 8)) & 0xffu;
      u32 pk[4];
      #pragma unroll
      for (int t2i = 0; t2i < 4; ++t2i){
        h2 w = __builtin_elementwise_max(u2h2(es[t2i]), rr * u2h2(gs[t2i]));
        pk[t2i] = h22u(w) & smLut[(mb >> (2 * t2i)) & 3u];
      }
      half8 af = pk2h8(*(uint4*)pk);
      acc    = __builtin_amdgcn_mfma_f32_16x16x32_f16(af, bf, acc, 0, 0, 0);
      accden = __builtin_amdgcn_mfma_f32_16x16x32_f16(af, bden, accden, 0, 0, 0);
    }
  }
  #pragma unroll
  for (int r4 = 0; r4 < 4; ++r4){
    int n = iblk * 64 + wv * 16 + grp * 4 + r4;
    if (row16 == 0)
      pden[(size_t)n * 16 + split] = accden[r4];
    pnum[((size_t)n * 16 + split) * 16 + row16] = acc[r4];
  }
}

// ===== K5: combine + elu + log_softmax =====================================
__global__ __launch_bounds__(256) void k_final(const float* __restrict__ pnum,
                                               const float* __restrict__ pden,
                                               float* __restrict__ out){
  int tid = blockIdx.x * 256 + threadIdx.x;   // 65536
  int c = tid & 15;
  int n = tid >> 4;
  float num = 0.f, den = 0.f;
  #pragma unroll
  for (int s = 0; s < 16; ++s){
    num += pnum[((size_t)n * 16 + s) * 16 + c];
    den += pden[(size_t)n * 16 + s];
  }
  float v = num / den;
  v = v > 0.f ? v : (__expf(v) - 1.f);
  float m = v;
  #pragma unroll
  for (int d = 1; d < 16; d <<= 1) m = fmaxf(m, __shfl_xor(m, d, 64));
  float es = __expf(v - m), ss = es;
  #pragma unroll
  for (int d = 1; d < 16; d <<= 1) ss += __shfl_xor(ss, d, 64);
  out[(size_t)n * 16 + c] = v - m - __logf(ss);
}

// ---------------------------------------------------------------------------
extern "C" void kernel_launch(void* const* d_in, const int* in_sizes, int n_in,
                              void* d_out, int out_size, void* d_ws, size_t ws_size,
                              hipStream_t stream){
  (void)in_sizes; (void)n_in; (void)out_size; (void)ws_size;
  const float* x    = (const float*)d_in[0];
  const int*   adj  = (const int*)d_in[1];
  const float* W    = (const float*)d_in[2];
  const float* av   = (const float*)d_in[3];
  const float* Wout = (const float*)d_in[4];
  const float* aout = (const float*)d_in[5];
  float* out = (float*)d_out;
  char* ws = (char*)d_ws;

  u64*  bits_t  = (u64*)(ws + 0x0000000);        // 2 MB [64][4096]
  u16*  whB     = (u16*)(ws + 0x0200000);        // 4 MB f16 [8][j/8][o][8]
  float* r1     = (float*)(ws + 0x0600000);      // 128 KB
  u16*  e21h    = (u16*)(ws + 0x0620000);        // 64 KB f16
  u16*  e202h   = (u16*)(ws + 0x0630000);        // 64 KB f16
  u16*  pnum1   = (u16*)(ws + 0x0680000);        // 16 MB f16 [4][4096][512]
  float* pden1  = (float*)(ws + 0x1680000);      // 512 KB [4][8][4096]
  u16*  whoB    = (u16*)(ws + 0x1700000);        // 128 KB f16
  float* r1o    = (float*)(ws + 0x1720000);      // 16 KB
  u16*  e21oh   = (u16*)(ws + 0x1724000);        // 8 KB f16
  u16*  e202oh  = (u16*)(ws + 0x1726000);        // 8 KB f16
  float* pnum2  = (float*)(ws + 0x1730000);      // 4 MB [4096][16][16]
  float* pden2  = (float*)(ws + 0x1B30000);      // 256 KB

  k_gemm1<<<dim3(64, 8), dim3(256), 0, stream>>>(x, W, av, adj, whB, bits_t, r1, e21h, e202h);
  k_att1<<<dim3(64, 8, 4), dim3(256), 0, stream>>>(whB, bits_t, r1, e21h, e202h, pnum1, pden1);
  k_gemm2<<<dim3(256), dim3(256), 0, stream>>>(pnum1, pden1, Wout, aout, whoB, r1o, e21oh, e202oh);
  k_att2<<<dim3(64, 16), dim3(256), 0, stream>>>(whoB, bits_t, r1o, e21oh, e202oh, pnum2, pden2);
  k_final<<<dim3(256), dim3(256), 0, stream>>>(pnum2, pden2, out);
}